// Round 4
// baseline (424.893 us; speedup 1.0000x reference)
//
#include <hip/hip_runtime.h>
#include <math.h>

#define BB 32
#define NN 8400
#define MM 32
#define NC 80
#define PD 85
#define TOPK 10
#define NCHUNK 8
#define CHSZ 1050            // NN / NCHUNK
#define FLT_BIG 3.4e38f

__device__ __forceinline__ float sigmoidf_(float x) { return 1.0f / (1.0f + expf(-x)); }
__device__ __forceinline__ float bcef_(float x, float t) {
    return fmaxf(x, 0.0f) - x * t + log1pf(expf(-fabsf(x)));
}

// ---- Kernel AB: wave-per-2-rows, zero LDS, fully coalesced ----------------
// A wave owns rows (r0, r0+1) = 170 contiguous floats, loaded as 3 coalesced
// wave-reads into x0/x1/x2. Class terms computed one-per-lane (parallel, not
// 80-serial), base via shfl_xor tree. Class gather = __shfl with runtime lane.
// GT phase: lane -> (row half rs = lane>>5, g = lane&31); store is 64
// contiguous float2 {cost, viou} in [b][n][g] layout = 512B coalesced.
__global__ void __launch_bounds__(256) kAB(const float* __restrict__ pred,
                                           const float* __restrict__ tgt,
                                           float2* __restrict__ cv2) {
    const int lane = threadIdx.x & 63;
    const int gw = blockIdx.x * (blockDim.x >> 6) + (threadIdx.x >> 6);
    const int nw = gridDim.x * (blockDim.x >> 6);
    const int rs = lane >> 5, g = lane & 31;
    const int NPAIR = BB * (NN / 2);

    for (int pair = gw; pair < NPAIR; pair += nw) {
        const int b = pair / (NN / 2);
        const int r0 = (pair - b * (NN / 2)) * 2;
        const size_t off = ((size_t)b * NN + r0) * PD;
        float x0 = pred[off + lane];                       // pos = lane      (0..63)
        float x1 = pred[off + 64 + lane];                  // pos = 64+lane   (64..127)
        float x2 = (lane < 42) ? pred[off + 128 + lane] : 0.0f; // pos 128..169

        // row headers: row0 at pos 0..4 (x0 lanes 0-4), row1 at pos 85..89 (x1 lanes 21-25)
        float cx0 = __shfl(x0, 0), cy0 = __shfl(x0, 1), w0 = __shfl(x0, 2), h0 = __shfl(x0, 3), ol0 = __shfl(x0, 4);
        float cx1 = __shfl(x1, 21), cy1 = __shfl(x1, 22), w1 = __shfl(x1, 23), h1 = __shfl(x1, 24), ol1 = __shfl(x1, 25);
        float so0 = sigmoidf_(ol0), so1 = sigmoidf_(ol1);

        // class lq terms: row0 classes = pos 5..84, row1 classes = pos 90..169
        float a0 = 0.0f, a1 = 0.0f;
        if (lane >= 5)  a0 += logf(1.0f - sqrtf(sigmoidf_(x0) * so0) + 1e-7f);  // c = lane-5
        if (lane < 21)  a0 += logf(1.0f - sqrtf(sigmoidf_(x1) * so0) + 1e-7f);  // c = 59+lane
        if (lane >= 26) a1 += logf(1.0f - sqrtf(sigmoidf_(x1) * so1) + 1e-7f);  // c = lane-26
        if (lane < 42)  a1 += logf(1.0f - sqrtf(sigmoidf_(x2) * so1) + 1e-7f);  // c = 38+lane
        #pragma unroll
        for (int o = 32; o; o >>= 1) { a0 += __shfl_xor(a0, o); a1 += __shfl_xor(a1, o); }
        float base0 = -a0, base1 = -a1;

        // per-lane row selection
        float cxs = rs ? cx1 : cx0, cys = rs ? cy1 : cy0;
        float ws_ = rs ? w1 : w0, hs_ = rs ? h1 : h0;
        float sos = rs ? so1 : so0, bases = rs ? base1 : base0;
        float px1 = cxs - ws_ * 0.5f, py1 = cys - hs_ * 0.5f;
        float px2 = cxs + ws_ * 0.5f, py2 = cys + hs_ * 0.5f;
        float pa = fmaxf(px2 - px1, 0.0f) * fmaxf(py2 - py1, 0.0f);

        // GT data (tiny, L1-resident)
        const float* t = tgt + ((size_t)b * MM + g) * 5;
        int gcls = (int)t[0];
        float gx1 = t[1] - t[3] * 0.5f, gy1 = t[2] - t[4] * 0.5f;
        float gx2 = t[1] + t[3] * 0.5f, gy2 = t[2] + t[4] * 0.5f;
        float ga = fmaxf(gx2 - gx1, 0.0f) * fmaxf(gy2 - gy1, 0.0f);

        // gather class logit p_rs[5 + gcls] from wave registers
        int posn = rs * 85 + 5 + gcls;                     // <= 169
        int k = posn >> 6, ls = posn & 63;
        float g0 = __shfl(x0, ls), g1 = __shfl(x1, ls), g2 = __shfl(x2, ls);
        float cl = (k == 0) ? g0 : ((k == 1) ? g1 : g2);

        float ix1 = fmaxf(gx1, px1), iy1 = fmaxf(gy1, py1);
        float ix2 = fminf(gx2, px2), iy2 = fminf(gy2, py2);
        float inter = fmaxf(ix2 - ix1, 0.0f) * fmaxf(iy2 - iy1, 0.0f);
        float uni = ga + pa - inter + 1e-7f;
        float iou = inter / uni;
        bool inb = (cxs > gx1) && (cxs < gx2) && (cys > gy1) && (cys < gy2);
        float s = sqrtf(sigmoidf_(cl) * sos);
        float lp = logf(s + 1e-7f);
        float lq = logf(1.0f - s + 1e-7f);
        float cc = bases - lp + lq;
        float co = cc + 3.0f * (-logf(iou + 1e-8f)) + (inb ? 0.0f : 100000.0f);

        // [b][n][g] layout: element (b*NN+r0)*32 + rs*32 + g = base + lane
        cv2[((size_t)b * NN + r0) * MM + lane] = make_float2(co, inb ? iou : 0.0f);
    }
}

// ---- Kernel C1: per-(image, n-chunk) exact partial top-10 lists -----------
// Coalesced float2 scan; per-thread register lists; per-g merge of 8 threads.
__global__ void __launch_bounds__(256) kC1(const float2* __restrict__ cv2,
                                           float* __restrict__ piou,
                                           float2* __restrict__ pcvn) {
    const int chunk = blockIdx.x, b = blockIdx.y;
    const int t = threadIdx.x;
    const int g = t & 31, sub = t >> 5;      // 8 n-lanes per g
    const int c0 = chunk * CHSZ;

    float ti[TOPK], cv[TOPK]; int ci[TOPK];
    #pragma unroll
    for (int j = 0; j < TOPK; ++j) { ti[j] = -1.0f; cv[j] = FLT_BIG; ci[j] = 0x7fffffff; }

    const float2* basep = cv2 + ((size_t)b * NN + c0) * MM + g;
    for (int n = sub; n < CHSZ; n += 8) {     // per-thread n strictly increasing
        float2 e = basep[(size_t)n * MM];
        float c = e.x, v = e.y;
        if (v > ti[TOPK - 1]) {
            ti[TOPK - 1] = v;
            #pragma unroll
            for (int j = TOPK - 1; j > 0; --j)
                if (ti[j] > ti[j - 1]) { float tmp = ti[j - 1]; ti[j - 1] = ti[j]; ti[j] = tmp; }
        }
        if (c < cv[TOPK - 1]) {               // strict <: equal cost keeps smaller n
            cv[TOPK - 1] = c; ci[TOPK - 1] = c0 + n;
            #pragma unroll
            for (int j = TOPK - 1; j > 0; --j)
                if (cv[j] < cv[j - 1]) {
                    float tv = cv[j - 1]; cv[j - 1] = cv[j]; cv[j] = tv;
                    int tn = ci[j - 1]; ci[j - 1] = ci[j]; ci[j] = tn;
                }
        }
    }

    __shared__ float siou[256 * TOPK];
    __shared__ float scv[256 * TOPK];
    __shared__ int   scn[256 * TOPK];
    #pragma unroll
    for (int j = 0; j < TOPK; ++j) {
        siou[t * TOPK + j] = ti[j];
        scv[t * TOPK + j] = cv[j];
        scn[t * TOPK + j] = ci[j];
    }
    __syncthreads();

    if (t < 32) {   // merge the 8 sub-lists for g = t (exact: disjoint n sets)
        float mi[TOPK], mc[TOPK]; int mn[TOPK];
        #pragma unroll
        for (int j = 0; j < TOPK; ++j) { mi[j] = -1.0f; mc[j] = FLT_BIG; mn[j] = 0x7fffffff; }
        for (int sidx = 0; sidx < 8; ++sidx) {
            int src = (t + sidx * 32) * TOPK;
            #pragma unroll
            for (int j = 0; j < TOPK; ++j) {
                float v = siou[src + j];
                if (v > mi[TOPK - 1]) {        // value-multiset exact under strict >
                    mi[TOPK - 1] = v;
                    #pragma unroll
                    for (int q = TOPK - 1; q > 0; --q)
                        if (mi[q] > mi[q - 1]) { float tm = mi[q - 1]; mi[q - 1] = mi[q]; mi[q] = tm; }
                }
                float c = scv[src + j]; int n2 = scn[src + j];
                if (c < mc[TOPK - 1] || (c == mc[TOPK - 1] && n2 < mn[TOPK - 1])) {
                    mc[TOPK - 1] = c; mn[TOPK - 1] = n2;
                    #pragma unroll
                    for (int q = TOPK - 1; q > 0; --q)
                        if (mc[q] < mc[q - 1] || (mc[q] == mc[q - 1] && mn[q] < mn[q - 1])) {
                            float tv = mc[q - 1]; mc[q - 1] = mc[q]; mc[q] = tv;
                            int tn = mn[q - 1]; mn[q - 1] = mn[q]; mn[q] = tn;
                        }
                }
            }
        }
        size_t po = (((size_t)b * NCHUNK + chunk) * MM + t) * TOPK;
        #pragma unroll
        for (int j = 0; j < TOPK; ++j) {
            piou[po + j] = mi[j];
            pcvn[po + j] = make_float2(mc[j], __int_as_float(mn[j]));
        }
    }
}

// ---- Kernel C2: per-(b,g) final merge -> dyn_k + assignment ---------------
__global__ void __launch_bounds__(64) kC2(const float* __restrict__ piou,
                                          const float2* __restrict__ pcvn,
                                          unsigned int* __restrict__ mask) {
    const int g = blockIdx.x, b = blockIdx.y, lane = threadIdx.x;
    const int NCAND = NCHUNK * TOPK;   // 80
    __shared__ float civ[NCAND];
    __shared__ float ccv[NCAND];
    __shared__ int   ccn[NCAND];
    for (int i = lane; i < NCAND; i += 64) {
        int ch = i / TOPK, j = i - ch * TOPK;
        size_t po = (((size_t)b * NCHUNK + ch) * MM + g) * TOPK + j;
        civ[i] = piou[po];
        float2 e = pcvn[po];
        ccv[i] = e.x; ccn[i] = __float_as_int(e.y);
    }
    __syncthreads();

    // sum of top-10 ious, accumulated in descending order (matches ref)
    float ssum = 0.0f;
    for (int p = 0; p < TOPK; ++p) {
        float bv = -2.0f; int bp = 0x7fffffff;
        for (int i = lane; i < NCAND; i += 64) {
            float v = civ[i];
            if (v > bv) { bv = v; bp = i; }
        }
        #pragma unroll
        for (int o = 32; o; o >>= 1) {
            float ov = __shfl_xor(bv, o); int op = __shfl_xor(bp, o);
            if (ov > bv || (ov == bv && op < bp)) { bv = ov; bp = op; }
        }
        ssum += bv;
        if (lane == 0) civ[bp] = -2.0f;
        __syncthreads();
    }
    int dynk = (int)ssum;              // trunc toward zero; sum in [0,10)
    if (dynk < 1) dynk = 1;
    if (dynk > TOPK) dynk = TOPK;

    // dyn_k lexicographically-smallest (cost, n)
    for (int p = 0; p < dynk; ++p) {
        float bv = FLT_BIG; int bn = 0x7fffffff, bp = -1;
        for (int i = lane; i < NCAND; i += 64) {
            float v = ccv[i]; int n2 = ccn[i];
            if (v < bv || (v == bv && n2 < bn)) { bv = v; bn = n2; bp = i; }
        }
        #pragma unroll
        for (int o = 32; o; o >>= 1) {
            float ov = __shfl_xor(bv, o); int on = __shfl_xor(bn, o); int op = __shfl_xor(bp, o);
            if (ov < bv || (ov == bv && on < bn)) { bv = ov; bn = on; bp = op; }
        }
        if (lane == 0) {
            ccv[bp] = FLT_BIG; ccn[bp] = 0x7fffffff;
            if (bv < 5.0e4f)   // assigned requires in_box (in-box cost << 5e4)
                atomicOr(&mask[(size_t)b * NN + bn], 1u << g);
        }
        __syncthreads();
    }
}

// ---- Kernel D: per-prediction losses -> per-block partials ---------------
__global__ void kD(const float* __restrict__ pred, const float* __restrict__ tgt,
                   const unsigned int* __restrict__ mask,
                   const float2* __restrict__ cv2, float* __restrict__ partials) {
    int i = blockIdx.x * 256 + threadIdx.x;
    float obj_l = 0.0f, cls_l = 0.0f, reg_l = 0.0f, nfg = 0.0f;
    if (i < BB * NN) {
        int b = i / NN;
        unsigned int mk = mask[i];
        float fg = mk ? 1.0f : 0.0f;
        const float* p = pred + (size_t)i * PD;
        obj_l = bcef_(p[4], fg);
        if (mk) {
            nfg = 1.0f;
            float best = 3.0e30f;
            int bg = 0;
            for (int g = 0; g < MM; ++g) {
                if ((mk >> g) & 1u) {
                    float cvv = cv2[(size_t)i * MM + g].x;
                    if (cvv < best) { best = cvv; bg = g; }  // first-min tie rule
                }
            }
            const float* t = tgt + ((size_t)b * MM + bg) * 5;
            int gcls = (int)t[0];
            for (int c = 0; c < NC; ++c)
                cls_l += bcef_(p[5 + c], (c == gcls) ? 1.0f : 0.0f);
            float cx = p[0], cy = p[1], w = p[2], h = p[3];
            float px1 = cx - w * 0.5f, py1 = cy - h * 0.5f;
            float px2 = cx + w * 0.5f, py2 = cy + h * 0.5f;
            float tx1 = t[1] - t[3] * 0.5f, ty1 = t[2] - t[4] * 0.5f;
            float tx2 = t[1] + t[3] * 0.5f, ty2 = t[2] + t[4] * 0.5f;
            float ix1 = fmaxf(px1, tx1), iy1 = fmaxf(py1, ty1);
            float ix2 = fminf(px2, tx2), iy2 = fminf(py2, ty2);
            float inter = fmaxf(ix2 - ix1, 0.0f) * fmaxf(iy2 - iy1, 0.0f);
            float pa = fmaxf(px2 - px1, 0.0f) * fmaxf(py2 - py1, 0.0f);
            float ta = fmaxf(tx2 - tx1, 0.0f) * fmaxf(ty2 - ty1, 0.0f);
            float uni = pa + ta - inter + 1e-7f;
            float iou = inter / uni;
            float ex1 = fminf(px1, tx1), ey1 = fminf(py1, ty1);
            float ex2 = fmaxf(px2, tx2), ey2 = fmaxf(py2, ty2);
            float enclose = (ex2 - ex1) * (ey2 - ey1) + 1e-7f;
            float giou = iou - (enclose - uni) / enclose;
            reg_l = 1.0f - giou;
        }
    }
    __shared__ float red[256];
    float sums[4] = {cls_l, obj_l, reg_l, nfg};
    float out4[4];
    for (int j = 0; j < 4; ++j) {
        red[threadIdx.x] = sums[j];
        __syncthreads();
        for (int off = 128; off > 0; off >>= 1) {
            if (threadIdx.x < off) red[threadIdx.x] += red[threadIdx.x + off];
            __syncthreads();
        }
        out4[j] = red[0];
        __syncthreads();
    }
    if (threadIdx.x == 0) {
        float* pr = partials + (size_t)blockIdx.x * 4;
        pr[0] = out4[0]; pr[1] = out4[1]; pr[2] = out4[2]; pr[3] = out4[3];
    }
}

// ---- Kernel E: final deterministic reduction -----------------------------
__global__ void kE(const float* __restrict__ partials, int nblk, float* __restrict__ out) {
    __shared__ float red[256];
    float s[4] = {0, 0, 0, 0};
    for (int i = threadIdx.x; i < nblk; i += 256) {
        s[0] += partials[(size_t)i * 4 + 0];
        s[1] += partials[(size_t)i * 4 + 1];
        s[2] += partials[(size_t)i * 4 + 2];
        s[3] += partials[(size_t)i * 4 + 3];
    }
    float tot[4];
    for (int j = 0; j < 4; ++j) {
        red[threadIdx.x] = s[j];
        __syncthreads();
        for (int off = 128; off > 0; off >>= 1) {
            if (threadIdx.x < off) red[threadIdx.x] += red[threadIdx.x + off];
            __syncthreads();
        }
        tot[j] = red[0];
        __syncthreads();
    }
    if (threadIdx.x == 0) {
        float nfg = fmaxf(tot[3], 1.0f);
        out[0] = (tot[0] + tot[1] + 5.0f * tot[2]) / nfg;
    }
}

extern "C" void kernel_launch(void* const* d_in, const int* in_sizes, int n_in,
                              void* d_out, int out_size, void* d_ws, size_t ws_size,
                              hipStream_t stream) {
    const float* pred = (const float*)d_in[0];   // (B, N, 85) f32
    const float* tgt  = (const float*)d_in[1];   // (B, M, 5)  f32
    float* out = (float*)d_out;

    // Workspace layout (~70.9 MB)
    char* ws = (char*)d_ws;
    size_t off = 0;
    float2* cv2 = (float2*)(ws + off);              off += (size_t)BB * NN * MM * sizeof(float2);
    unsigned int* mask = (unsigned int*)(ws + off); off += (size_t)BB * NN * sizeof(unsigned int);
    float* piou = (float*)(ws + off);               off += (size_t)BB * NCHUNK * MM * TOPK * sizeof(float);
    float2* pcvn = (float2*)(ws + off);             off += (size_t)BB * NCHUNK * MM * TOPK * sizeof(float2);
    float* partials = (float*)(ws + off);

    const int nblk = (BB * NN + 255) / 256;  // 1050

    // mask accumulates via atomicOr -> zero every call
    hipMemsetAsync(mask, 0, (size_t)BB * NN * sizeof(unsigned int), stream);

    kAB<<<2048, 256, 0, stream>>>(pred, tgt, cv2);

    dim3 gC1(NCHUNK, BB);                    // 8 x 32 = 256 blocks
    kC1<<<gC1, 256, 0, stream>>>(cv2, piou, pcvn);

    dim3 gC2(MM, BB);                        // 32 x 32
    kC2<<<gC2, 64, 0, stream>>>(piou, pcvn, mask);

    kD<<<nblk, 256, 0, stream>>>(pred, tgt, mask, cv2, partials);

    kE<<<1, 256, 0, stream>>>(partials, nblk, out);
}